// Round 1
// baseline (367.615 us; speedup 1.0000x reference)
//
#include <hip/hip_runtime.h>
#include <hip/hip_bf16.h>
#include <math.h>

// Problem constants (from reference setup_inputs): x[32,1024,2048] f32,
// W[1024,1024] f32, b[1024] f32, out[32,1024] f32.
#define BB 32
#define CC 1024
#define LL 2048

// Kernel 1: s[b,c] = sum_l x[b,c,l]. One wave (64 lanes) per row.
// Row = 2048 f32 = 512 float4; each lane does 8 coalesced float4 loads.
__global__ __launch_bounds__(256) void sum_rows_kernel(
    const float* __restrict__ x, float* __restrict__ s) {
    const int wid  = (blockIdx.x * blockDim.x + threadIdx.x) >> 6;  // row id
    const int lane = threadIdx.x & 63;
    if (wid >= BB * CC) return;
    const float4* p = reinterpret_cast<const float4*>(x + (size_t)wid * LL);
    float acc = 0.0f;
#pragma unroll
    for (int i = 0; i < (LL / 4) / 64; ++i) {
        float4 v = p[lane + i * 64];
        acc += v.x + v.y + v.z + v.w;
    }
#pragma unroll
    for (int off = 32; off > 0; off >>= 1) acc += __shfl_down(acc, off);
    if (lane == 0) s[wid] = acc;
}

// Kernel 2: y[b,o] = dot(W[o,:], s[b,:]) + L*bias[o]; out = mish(y).
// One wave per (b,o) output. 1024 f32 = 256 float4; 4 iters/lane.
__global__ __launch_bounds__(256) void gemm_mish_kernel(
    const float* __restrict__ s, const float* __restrict__ W,
    const float* __restrict__ bias, float* __restrict__ out) {
    const int wid  = (blockIdx.x * blockDim.x + threadIdx.x) >> 6;
    const int lane = threadIdx.x & 63;
    if (wid >= BB * CC) return;
    const int bb = wid >> 10;    // batch index
    const int oo = wid & 1023;   // output channel
    const float4* wp = reinterpret_cast<const float4*>(W + (size_t)oo * CC);
    const float4* sp = reinterpret_cast<const float4*>(s + (size_t)bb * CC);
    float acc = 0.0f;
#pragma unroll
    for (int i = 0; i < (CC / 4) / 64; ++i) {
        float4 wv = wp[lane + i * 64];
        float4 sv = sp[lane + i * 64];
        acc += wv.x * sv.x + wv.y * sv.y + wv.z * sv.z + wv.w * sv.w;
    }
#pragma unroll
    for (int off = 32; off > 0; off >>= 1) acc += __shfl_down(acc, off);
    if (lane == 0) {
        float y = acc + (float)LL * bias[oo];
        // stable softplus: log1p(exp(y)) overflows for y > ~88
        float sp_ = (y > 20.0f) ? y : log1pf(expf(y));
        out[wid] = y * tanhf(sp_);
    }
}

extern "C" void kernel_launch(void* const* d_in, const int* in_sizes, int n_in,
                              void* d_out, int out_size, void* d_ws, size_t ws_size,
                              hipStream_t stream) {
    const float* x    = (const float*)d_in[0];
    const float* W    = (const float*)d_in[1];
    const float* bias = (const float*)d_in[2];
    float* out        = (float*)d_out;
    float* s          = (float*)d_ws;  // 32*1024 f32 = 128 KB scratch

    // Kernel 1: 32768 waves -> 8192 blocks of 256 threads (4 waves each)
    {
        const int waves  = BB * CC;
        const int blocks = waves * 64 / 256;
        sum_rows_kernel<<<blocks, 256, 0, stream>>>(x, s);
    }
    // Kernel 2: 32768 waves -> 8192 blocks
    {
        const int waves  = BB * CC;
        const int blocks = waves * 64 / 256;
        gemm_mish_kernel<<<blocks, 256, 0, stream>>>(s, W, bias, out);
    }
}